// Round 1
// baseline (216.623 us; speedup 1.0000x reference)
//
#include <hip/hip_runtime.h>
#include <stdint.h>

typedef _Float16 half_t;
typedef __attribute__((ext_vector_type(8))) _Float16 f16x8;
typedef __attribute__((ext_vector_type(4))) _Float16 f16x4;
typedef __attribute__((ext_vector_type(4))) float f32x4;

#define SQN 4096
#define SKN 16448
#define NROPE 16384
#define NSPLIT 8
#define NTILES 514   // 16448 / 32 exactly
#define TPC 65       // ceil(514/8)

// f32 -> f16 via cast (RNE). f16 -> f32 implicit.

// ---------------- weight transpose: W[k][n] f32 -> WT[n][k] f16 (4 mats) ------
__global__ __launch_bounds__(256) void wt_kernel(const float* __restrict__ qw,
    const float* __restrict__ kw, const float* __restrict__ vw, const float* __restrict__ ow,
    half_t* __restrict__ wt)
{
    __shared__ float tile[64][65];
    int b = blockIdx.x;
    int mat = b >> 4, t4 = b & 15;
    int k0 = (t4 >> 2) << 6, n0 = (t4 & 3) << 6;
    const float* W = (mat == 0) ? qw : (mat == 1) ? kw : (mat == 2) ? vw : ow;
    half_t* WT = wt + mat * 65536;
    int t = threadIdx.x;
#pragma unroll
    for (int j = 0; j < 16; ++j) {
        int e = j * 256 + t;
        tile[e >> 6][e & 63] = W[(k0 + (e >> 6)) * 256 + n0 + (e & 63)];
    }
    __syncthreads();
#pragma unroll
    for (int j = 0; j < 16; ++j) {
        int e = j * 256 + t;
        WT[(n0 + (e >> 6)) * 256 + k0 + (e & 63)] = (half_t)tile[e & 63][e >> 6];
    }
}

// ---------------- fused QKV projection + bias + RoPE -------------------------
// grid: 64 (Q) + 257 (K) + 257 (V) = 578 blocks, 256 threads (4 waves x 16 rows)
__global__ __launch_bounds__(256) void proj_kernel(
    const float* __restrict__ query, const float* __restrict__ key, const float* __restrict__ value,
    const float* __restrict__ cosp, const float* __restrict__ sinp,
    const half_t* __restrict__ wt,
    const float* __restrict__ qb, const float* __restrict__ kb, const float* __restrict__ vb,
    half_t* __restrict__ Qe, half_t* __restrict__ Ke, half_t* __restrict__ VT)
{
    __shared__ __align__(16) half_t Ws[256 * 40];   // [n][k-chunk 32, pad to 40]
    int b = blockIdx.x;
    int mode; long row0;
    const float* X; const half_t* W; const float* bias;
    if (b < 64)       { mode = 0; row0 = (long)b * 64;         X = query; W = wt;           bias = qb; }
    else if (b < 321) { mode = 1; row0 = (long)(b - 64) * 64;  X = key;   W = wt + 65536;   bias = kb; }
    else              { mode = 2; row0 = (long)(b - 321) * 64; X = value; W = wt + 131072;  bias = vb; }

    int tid = threadIdx.x;
    int w = tid >> 6, l = tid & 63;
    int l16 = l & 15, l4 = l >> 4;
    long rw0 = row0 + w * 16;

    f32x4 acc[16];
#pragma unroll
    for (int i = 0; i < 16; ++i) acc[i] = (f32x4){0.f, 0.f, 0.f, 0.f};

    for (int ks = 0; ks < 8; ++ks) {
        __syncthreads();
        {   // stage W[:, ks*32 .. +32] -> Ws[n][k]
            const f16x8* src = reinterpret_cast<const f16x8*>(W + tid * 256 + ks * 32);
            f16x8* dst = reinterpret_cast<f16x8*>(Ws + tid * 40);
            dst[0] = src[0]; dst[1] = src[1]; dst[2] = src[2]; dst[3] = src[3];
        }
        __syncthreads();
        const float* xp = X + (rw0 + l16) * 256 + ks * 32 + l4 * 8;
        f32x4 xa = *reinterpret_cast<const f32x4*>(xp);
        f32x4 xb = *reinterpret_cast<const f32x4*>(xp + 4);
        f16x8 af;
#pragma unroll
        for (int j = 0; j < 4; ++j) { af[j] = (half_t)xa[j]; af[4 + j] = (half_t)xb[j]; }
#pragma unroll
        for (int nt = 0; nt < 16; ++nt) {
            f16x8 bf = *reinterpret_cast<const f16x8*>(Ws + (nt * 16 + l16) * 40 + l4 * 8);
            acc[nt] = __builtin_amdgcn_mfma_f32_16x16x32_f16(af, bf, acc[nt], 0, 0, 0);
        }
    }

    bool dorope = (mode == 0) || (mode == 1 && row0 < NROPE);
#pragma unroll
    for (int nt = 0; nt < 16; ++nt) {
        int d = nt * 16 + l16;
        float bv = bias[d];
        f32x4 v = acc[nt];
#pragma unroll
        for (int r = 0; r < 4; ++r) v[r] += bv;
        if (dorope) {
#pragma unroll
            for (int r = 0; r < 4; ++r) {
                long m = rw0 + l4 * 4 + r;
                long crow = (mode == 0) ? m : (m >> 2);
                float c = cosp[crow * 256 + d];
                float s = sinp[crow * 256 + d];
                float val = v[r];
                float other = __shfl_xor(val, 1);
                float rot = (d & 1) ? other : -other;
                v[r] = val * c + rot * s;
            }
        }
        if (mode == 2) {        // V stored transposed: VT[d][kv]
            f16x4 pk;
#pragma unroll
            for (int r = 0; r < 4; ++r) pk[r] = (half_t)v[r];
            *reinterpret_cast<f16x4*>(VT + (long)d * SKN + rw0 + l4 * 4) = pk;
        } else {
            half_t* O = (mode == 0) ? Qe : Ke;
#pragma unroll
            for (int r = 0; r < 4; ++r)
                O[(rw0 + l4 * 4 + r) * 256 + d] = (half_t)v[r];
        }
    }
}

// ---------------- flash attention with KV-split ------------------------------
// grid: 32 q-blocks x 8 kv-chunks = 256 blocks, 512 threads (8 waves x 16 q rows)
__global__ __launch_bounds__(512) void flash_kernel(
    const half_t* __restrict__ Qe, const half_t* __restrict__ Ke, const half_t* __restrict__ VT,
    float* __restrict__ Op, float* __restrict__ Mp, float* __restrict__ Lp)
{
    __shared__ __align__(16) half_t Ks[32 * 264];   // [kv][d 256, pad 264]
    __shared__ __align__(16) half_t Vs[256 * 40];   // [d][kv 32, pad 40]
    __shared__ __align__(16) half_t Ps[8][16 * 40]; // per-wave P [q][kv 32, pad 40]

    int b = blockIdx.x;
    int qb = b & 31;
    int chunk = b >> 5;
    int tid = threadIdx.x;
    int w = tid >> 6, l = tid & 63;
    int l16 = l & 15, l4 = l >> 4;
    long qw0 = (long)qb * 128 + w * 16;

    f16x8 qf[8];    // Q as B-operand: lane holds Q[qw0+l16][ks*32 + l4*8 ..+8]
#pragma unroll
    for (int ks = 0; ks < 8; ++ks)
        qf[ks] = *reinterpret_cast<const f16x8*>(Qe + (qw0 + l16) * 256 + ks * 32 + l4 * 8);

    f32x4 o[16];
#pragma unroll
    for (int i = 0; i < 16; ++i) o[i] = (f32x4){0.f, 0.f, 0.f, 0.f};
    float mrun = -3.0e38f;
    float lsum = 0.0f;

    int t0 = chunk * TPC;
    int t1 = t0 + TPC; if (t1 > NTILES) t1 = NTILES;
    const float SC = 0.090168441360f;   // log2(e)/16
    half_t* Pw = Ps[w];

    for (int t = t0; t < t1; ++t) {
        long kv0 = (long)t * 32;
        __syncthreads();
        {   // stage K tile [32][256]
            int r = tid >> 4, seg = tid & 15;
            const f16x8* src = reinterpret_cast<const f16x8*>(Ke + (kv0 + r) * 256 + seg * 16);
            f16x8* dst = reinterpret_cast<f16x8*>(Ks + r * 264 + seg * 16);
            dst[0] = src[0]; dst[1] = src[1];
        }
        {   // stage V tile transposed-source: Vs[d][32]
            int d = tid >> 1, seg = tid & 1;
            const f16x8* src = reinterpret_cast<const f16x8*>(VT + (long)d * SKN + kv0 + seg * 16);
            f16x8* dst = reinterpret_cast<f16x8*>(Vs + d * 40 + seg * 16);
            dst[0] = src[0]; dst[1] = src[1];
        }
        __syncthreads();

        // swapped QK^T: S^T[kv][q] ; lane: col=q=l16, row=kv=kvm*16+l4*4+r
        f32x4 s0 = (f32x4){0.f, 0.f, 0.f, 0.f};
        f32x4 s1 = (f32x4){0.f, 0.f, 0.f, 0.f};
#pragma unroll
        for (int ks = 0; ks < 8; ++ks) {
            f16x8 ka0 = *reinterpret_cast<const f16x8*>(Ks + l16 * 264 + ks * 32 + l4 * 8);
            f16x8 ka1 = *reinterpret_cast<const f16x8*>(Ks + (16 + l16) * 264 + ks * 32 + l4 * 8);
            s0 = __builtin_amdgcn_mfma_f32_16x16x32_f16(ka0, qf[ks], s0, 0, 0, 0);
            s1 = __builtin_amdgcn_mfma_f32_16x16x32_f16(ka1, qf[ks], s1, 0, 0, 0);
        }

        float tv[8];
#pragma unroll
        for (int r = 0; r < 4; ++r) { tv[r] = s0[r] * SC; tv[4 + r] = s1[r] * SC; }
        float pm = tv[0];
#pragma unroll
        for (int i = 1; i < 8; ++i) pm = fmaxf(pm, tv[i]);
        pm = fmaxf(pm, __shfl_xor(pm, 16));
        pm = fmaxf(pm, __shfl_xor(pm, 32));

        if (!__all(pm - mrun <= 8.0f)) {    // defer-max rescale
            float mn = fmaxf(mrun, pm);
            float alpha = __builtin_amdgcn_exp2f(mrun - mn);
            lsum *= alpha;
            float ao[4];
#pragma unroll
            for (int r = 0; r < 4; ++r) ao[r] = __shfl(alpha, l4 * 4 + r);
#pragma unroll
            for (int i = 0; i < 16; ++i)
#pragma unroll
                for (int r = 0; r < 4; ++r) o[i][r] *= ao[r];
            mrun = mn;
        }

        float p[8];
        float psum = 0.f;
#pragma unroll
        for (int i = 0; i < 8; ++i) { p[i] = __builtin_amdgcn_exp2f(tv[i] - mrun); psum += p[i]; }
        psum += __shfl_xor(psum, 16);
        psum += __shfl_xor(psum, 32);
        lsum += psum;

        f16x4 pk0, pk1;
#pragma unroll
        for (int r = 0; r < 4; ++r) { pk0[r] = (half_t)p[r]; pk1[r] = (half_t)p[4 + r]; }
        *reinterpret_cast<f16x4*>(Pw + l16 * 40 + l4 * 4) = pk0;
        *reinterpret_cast<f16x4*>(Pw + l16 * 40 + 16 + l4 * 4) = pk1;

        // PV: A = P[q][kv32] (one b128), B = V[kv][d] from Vs (contiguous)
        f16x8 pa = *reinterpret_cast<const f16x8*>(Pw + l16 * 40 + l4 * 8);
#pragma unroll
        for (int nt = 0; nt < 16; ++nt) {
            f16x8 vbf = *reinterpret_cast<const f16x8*>(Vs + (nt * 16 + l16) * 40 + l4 * 8);
            o[nt] = __builtin_amdgcn_mfma_f32_16x16x32_f16(pa, vbf, o[nt], 0, 0, 0);
        }
    }

    // write unnormalized partials
    float* Ob = Op + ((long)chunk * SQN + qw0) * 256;
#pragma unroll
    for (int nt = 0; nt < 16; ++nt)
#pragma unroll
        for (int r = 0; r < 4; ++r)
            Ob[(l4 * 4 + r) * 256 + nt * 16 + l16] = o[nt][r];
    if (l < 16) {
        Mp[(long)chunk * SQN + qw0 + l16] = mrun;
        Lp[(long)chunk * SQN + qw0 + l16] = lsum;
    }
}

// ---------------- combine KV-split partials -> AO (f16) ----------------------
__global__ __launch_bounds__(256) void reduce_kernel(
    const float* __restrict__ Op, const float* __restrict__ Mp, const float* __restrict__ Lp,
    half_t* __restrict__ AO)
{
    int tid = threadIdx.x;
    long q = (long)blockIdx.x * 4 + (tid >> 6);
    int d0 = (tid & 63) * 4;
    float mi[NSPLIT];
    float mstar = -3.0e38f;
#pragma unroll
    for (int i = 0; i < NSPLIT; ++i) { mi[i] = Mp[i * SQN + q]; mstar = fmaxf(mstar, mi[i]); }
    f32x4 acc = (f32x4){0.f, 0.f, 0.f, 0.f};
    float lsum = 0.f;
#pragma unroll
    for (int i = 0; i < NSPLIT; ++i) {
        float wgt = __builtin_amdgcn_exp2f(mi[i] - mstar);
        lsum += wgt * Lp[i * SQN + q];
        f32x4 ov = *reinterpret_cast<const f32x4*>(Op + ((long)i * SQN + q) * 256 + d0);
#pragma unroll
        for (int r = 0; r < 4; ++r) acc[r] += wgt * ov[r];
    }
    float inv = 1.0f / lsum;
    f16x4 pk;
#pragma unroll
    for (int r = 0; r < 4; ++r) pk[r] = (half_t)(acc[r] * inv);
    *reinterpret_cast<f16x4*>(AO + q * 256 + d0) = pk;
}

// ---------------- O projection ----------------------------------------------
__global__ __launch_bounds__(256) void oproj_kernel(
    const half_t* __restrict__ AO, const half_t* __restrict__ WTo,
    const float* __restrict__ ob, float* __restrict__ out)
{
    int b = blockIdx.x;
    int tid = threadIdx.x;
    int w = tid >> 6, l = tid & 63;
    int l16 = l & 15, l4 = l >> 4;
    long r0 = (long)b * 64 + w * 16;
    f32x4 acc[16];
#pragma unroll
    for (int i = 0; i < 16; ++i) acc[i] = (f32x4){0.f, 0.f, 0.f, 0.f};
#pragma unroll
    for (int ks = 0; ks < 8; ++ks) {
        f16x8 af = *reinterpret_cast<const f16x8*>(AO + (r0 + l16) * 256 + ks * 32 + l4 * 8);
#pragma unroll
        for (int nt = 0; nt < 16; ++nt) {
            f16x8 bf = *reinterpret_cast<const f16x8*>(WTo + (nt * 16 + l16) * 256 + ks * 32 + l4 * 8);
            acc[nt] = __builtin_amdgcn_mfma_f32_16x16x32_f16(af, bf, acc[nt], 0, 0, 0);
        }
    }
#pragma unroll
    for (int nt = 0; nt < 16; ++nt) {
        int d = nt * 16 + l16;
        float bv = ob[d];
#pragma unroll
        for (int r = 0; r < 4; ++r)
            out[(r0 + l4 * 4 + r) * 256 + d] = acc[nt][r] + bv;
    }
}

extern "C" void kernel_launch(void* const* d_in, const int* in_sizes, int n_in,
                              void* d_out, int out_size, void* d_ws, size_t ws_size,
                              hipStream_t stream) {
    const float* query = (const float*)d_in[0];
    const float* key   = (const float*)d_in[1];
    const float* value = (const float*)d_in[2];
    const float* cosp  = (const float*)d_in[3];
    const float* sinp  = (const float*)d_in[4];
    const float* qw = (const float*)d_in[5];
    const float* qb = (const float*)d_in[6];
    const float* kw = (const float*)d_in[7];
    const float* kb = (const float*)d_in[8];
    const float* vw = (const float*)d_in[9];
    const float* vb = (const float*)d_in[10];
    const float* ow = (const float*)d_in[11];
    const float* ob = (const float*)d_in[12];

    char* ws = (char*)d_ws;
    half_t* Qe = (half_t*)(ws);                     // 4096*256*2    = 2,097,152
    half_t* Ke = (half_t*)(ws + 2097152);           // 16448*256*2   = 8,421,376
    half_t* VT = (half_t*)(ws + 10518528);          // 256*16448*2   = 8,421,376
    half_t* WT = (half_t*)(ws + 18939904);          // 4*256*256*2   = 524,288
    float*  Op = (float*)(ws + 19464192);           // 8*4096*256*4  = 33,554,432
    float*  Mp = (float*)(ws + 53018624);           // 8*4096*4
    float*  Lp = (float*)(ws + 53149696);           // 8*4096*4
    half_t* AO = (half_t*)(ws + 53280768);          // 4096*256*2
    // total ws use: 55,377,920 bytes

    hipLaunchKernelGGL(wt_kernel, dim3(64), dim3(256), 0, stream, qw, kw, vw, ow, WT);
    hipLaunchKernelGGL(proj_kernel, dim3(578), dim3(256), 0, stream,
                       query, key, value, cosp, sinp, WT, qb, kb, vb, Qe, Ke, VT);
    hipLaunchKernelGGL(flash_kernel, dim3(256), dim3(512), 0, stream, Qe, Ke, VT, Op, Mp, Lp);
    hipLaunchKernelGGL(reduce_kernel, dim3(1024), dim3(256), 0, stream, Op, Mp, Lp, AO);
    hipLaunchKernelGGL(oproj_kernel, dim3(64), dim3(256), 0, stream, AO, WT + 3 * 65536, ob, (float*)d_out);
}